// Round 1
// baseline (422.527 us; speedup 1.0000x reference)
//
#include <hip/hip_runtime.h>
#include <math.h>

// ---------------------------------------------------------------------------
// SingleHeadSelfAttention: B=4, S=2048, C=2048, d=512
// out = ((softmax((x Wqkv^T + bqkv -> q,k) q k^T / sqrt(d))) v) Wo^T + bo
// Strategy R0: bf16 MFMA for all 4 GEMMs via one generic gemm_bt kernel.
// ---------------------------------------------------------------------------

typedef __bf16 bf16;
typedef bf16 bf16x8 __attribute__((ext_vector_type(8)));
typedef bf16 bf16x4 __attribute__((ext_vector_type(4)));
typedef float f32x4 __attribute__((ext_vector_type(4)));

#define BB 4
#define SS 2048
#define CC 2048
#define DD 512
#define ND3 1536          // 3*DD
#define MM 8192           // BB*SS

// ---------------- fp32 -> bf16 conversion (vectorized, grid-stride) --------
__global__ __launch_bounds__(256) void cvt_f32_bf16(const float* __restrict__ in,
                                                    bf16* __restrict__ out, int n4) {
    int i = blockIdx.x * 256 + threadIdx.x;
    int stride = gridDim.x * 256;
    for (; i < n4; i += stride) {
        float4 v = ((const float4*)in)[i];
        bf16x4 o;
        o[0] = (bf16)v.x; o[1] = (bf16)v.y; o[2] = (bf16)v.z; o[3] = (bf16)v.w;
        ((bf16x4*)out)[i] = o;
    }
}

// ---------------- transpose v: qkv[b][j][1024+d] -> vT[b][d][j] ------------
__global__ void transpose_v(const bf16* __restrict__ qkv, bf16* __restrict__ vT) {
    __shared__ bf16 tile[32][33];
    int b = blockIdx.z;
    int j0 = blockIdx.x * 32, d0 = blockIdx.y * 32;
    const bf16* src = qkv + (size_t)b * SS * ND3 + 1024;
#pragma unroll
    for (int i = 0; i < 4; i++) {
        int j = j0 + threadIdx.y + i * 8;
        tile[threadIdx.y + i * 8][threadIdx.x] = src[(size_t)j * ND3 + d0 + threadIdx.x];
    }
    __syncthreads();
    bf16* dst = vT + (size_t)b * DD * SS;
#pragma unroll
    for (int i = 0; i < 4; i++) {
        int dd = d0 + threadIdx.y + i * 8;
        dst[(size_t)dd * SS + j0 + threadIdx.x] = tile[threadIdx.x][threadIdx.y + i * 8];
    }
}

// ---------------- row softmax: fp32 scores (2048 cols) -> bf16 probs -------
__global__ __launch_bounds__(256) void softmax_rows(const float* __restrict__ S,
                                                    bf16* __restrict__ P) {
    const int row = blockIdx.x;
    const float* src = S + (size_t)row * SS;
    bf16* dst = P + (size_t)row * SS;
    const int t = threadIdx.x;
    float4 v0 = ((const float4*)src)[t];
    float4 v1 = ((const float4*)src)[t + 256];
    float mx = fmaxf(fmaxf(fmaxf(v0.x, v0.y), fmaxf(v0.z, v0.w)),
                     fmaxf(fmaxf(v1.x, v1.y), fmaxf(v1.z, v1.w)));
#pragma unroll
    for (int off = 32; off; off >>= 1) mx = fmaxf(mx, __shfl_xor(mx, off, 64));
    __shared__ float redm[4], reds[4];
    if ((t & 63) == 0) redm[t >> 6] = mx;
    __syncthreads();
    mx = fmaxf(fmaxf(redm[0], redm[1]), fmaxf(redm[2], redm[3]));
    float e[8];
    e[0] = __expf(v0.x - mx); e[1] = __expf(v0.y - mx);
    e[2] = __expf(v0.z - mx); e[3] = __expf(v0.w - mx);
    e[4] = __expf(v1.x - mx); e[5] = __expf(v1.y - mx);
    e[6] = __expf(v1.z - mx); e[7] = __expf(v1.w - mx);
    float s = ((e[0] + e[1]) + (e[2] + e[3])) + ((e[4] + e[5]) + (e[6] + e[7]));
#pragma unroll
    for (int off = 32; off; off >>= 1) s += __shfl_xor(s, off, 64);
    if ((t & 63) == 0) reds[t >> 6] = s;
    __syncthreads();
    s = (reds[0] + reds[1]) + (reds[2] + reds[3]);
    float inv = 1.0f / s;
    bf16x4 o0, o1;
    o0[0] = (bf16)(e[0] * inv); o0[1] = (bf16)(e[1] * inv);
    o0[2] = (bf16)(e[2] * inv); o0[3] = (bf16)(e[3] * inv);
    o1[0] = (bf16)(e[4] * inv); o1[1] = (bf16)(e[5] * inv);
    o1[2] = (bf16)(e[6] * inv); o1[3] = (bf16)(e[7] * inv);
    ((bf16x4*)dst)[t] = o0;
    ((bf16x4*)dst)[t + 256] = o1;
}

// ---------------- generic C[m][n] = scale * sum_k A[m][k]B[n][k] + bias[n] -
// A: M x K bf16 (row-major, leading dim lda), B: N x K bf16 (ldb),
// C: M x N (ldc), fp32 or bf16 per template. Batched via blockIdx.z.
// 64x64 tile / block (4 waves, each 32x32 via 2x2 MFMA 16x16x32).
template <bool OUT_BF16>
__global__ __launch_bounds__(256) void gemm_bt(const bf16* __restrict__ A,
                                               const bf16* __restrict__ Bm,
                                               const float* __restrict__ bias,
                                               void* __restrict__ Cv,
                                               int K, int lda, int ldb, int ldc,
                                               long ab, long bb, long cb,
                                               float scale) {
    __shared__ bf16 As[64][40];   // BK=32 padded to 40 (+16B) for bank spread
    __shared__ bf16 Bs[64][40];
    A += (size_t)blockIdx.z * ab;
    Bm += (size_t)blockIdx.z * bb;
    const int m0 = blockIdx.y * 64, n0 = blockIdx.x * 64;
    const int t = threadIdx.x, lane = t & 63, w = t >> 6;
    const int wm = (w >> 1) * 32, wn = (w & 1) * 32;
    const int ld_row = t >> 2;        // 0..63
    const int ld_col = (t & 3) * 8;   // 0,8,16,24
    const int q = lane >> 4, cl = lane & 15;

    f32x4 acc[2][2] = {};
    for (int k0 = 0; k0 < K; k0 += 32) {
        bf16x8 av = *(const bf16x8*)&A[(size_t)(m0 + ld_row) * lda + k0 + ld_col];
        bf16x8 bv = *(const bf16x8*)&Bm[(size_t)(n0 + ld_row) * ldb + k0 + ld_col];
        *(bf16x8*)&As[ld_row][ld_col] = av;
        *(bf16x8*)&Bs[ld_row][ld_col] = bv;
        __syncthreads();
        bf16x8 a0 = *(const bf16x8*)&As[wm + cl][q * 8];
        bf16x8 a1 = *(const bf16x8*)&As[wm + 16 + cl][q * 8];
        bf16x8 b0 = *(const bf16x8*)&Bs[wn + cl][q * 8];
        bf16x8 b1 = *(const bf16x8*)&Bs[wn + 16 + cl][q * 8];
        acc[0][0] = __builtin_amdgcn_mfma_f32_16x16x32_bf16(a0, b0, acc[0][0], 0, 0, 0);
        acc[0][1] = __builtin_amdgcn_mfma_f32_16x16x32_bf16(a0, b1, acc[0][1], 0, 0, 0);
        acc[1][0] = __builtin_amdgcn_mfma_f32_16x16x32_bf16(a1, b0, acc[1][0], 0, 0, 0);
        acc[1][1] = __builtin_amdgcn_mfma_f32_16x16x32_bf16(a1, b1, acc[1][1], 0, 0, 0);
        __syncthreads();
    }
#pragma unroll
    for (int i = 0; i < 2; i++)
#pragma unroll
        for (int j = 0; j < 2; j++) {
            int col = n0 + wn + j * 16 + cl;
            float bvv = bias ? bias[col] : 0.0f;
#pragma unroll
            for (int r = 0; r < 4; r++) {
                int row = m0 + wm + i * 16 + q * 4 + r;
                float val = acc[i][j][r] * scale + bvv;
                if (OUT_BF16)
                    ((bf16*)Cv)[(size_t)blockIdx.z * cb + (size_t)row * ldc + col] = (bf16)val;
                else
                    ((float*)Cv)[(size_t)blockIdx.z * cb + (size_t)row * ldc + col] = val;
            }
        }
}

// ---------------------------------------------------------------------------
extern "C" void kernel_launch(void* const* d_in, const int* in_sizes, int n_in,
                              void* d_out, int out_size, void* d_ws, size_t ws_size,
                              hipStream_t stream) {
    const float* x    = (const float*)d_in[0];  // (4,2048,2048)
    const float* Wqkv = (const float*)d_in[1];  // (1536,2048)
    const float* bqkv = (const float*)d_in[2];  // (1536,)
    const float* Wo   = (const float*)d_in[3];  // (2048,512)
    const float* bo   = (const float*)d_in[4];  // (2048,)
    float* out = (float*)d_out;                 // (4,2048,2048) fp32

    char* ws = (char*)d_ws;
    size_t off = 0;
    bf16* xb    = (bf16*)(ws + off); off += (size_t)MM * CC * 2;       // 32 MB
    bf16* wqkvb = (bf16*)(ws + off); off += (size_t)ND3 * CC * 2;      // 6 MB
    bf16* wob   = (bf16*)(ws + off); off += (size_t)CC * DD * 2;       // 2 MB
    bf16* qkvb  = (bf16*)(ws + off); off += (size_t)MM * ND3 * 2;      // 24 MB
    bf16* vT    = (bf16*)(ws + off); off += (size_t)BB * DD * SS * 2;  // 8 MB
    float* scor = (float*)(ws + off); off += (size_t)BB * SS * SS * 4; // 64 MB
    bf16* probs = (bf16*)(ws + off); off += (size_t)BB * SS * SS * 2;  // 32 MB
    bf16* ctxb  = (bf16*)(ws + off); off += (size_t)MM * DD * 2;       // 8 MB

    // 1. convert inputs to bf16
    cvt_f32_bf16<<<4096, 256, 0, stream>>>(x, xb, MM * CC / 4);
    cvt_f32_bf16<<<1024, 256, 0, stream>>>(Wqkv, wqkvb, ND3 * CC / 4);
    cvt_f32_bf16<<<512, 256, 0, stream>>>(Wo, wob, CC * DD / 4);

    // 2. qkv = x Wqkv^T + bqkv   (M=8192, N=1536, K=2048) -> bf16
    gemm_bt<true><<<dim3(ND3 / 64, MM / 64, 1), 256, 0, stream>>>(
        xb, wqkvb, bqkv, qkvb, CC, CC, CC, ND3, 0, 0, 0, 1.0f);

    // 3. vT[b][d][j] = v[b][j][d]
    transpose_v<<<dim3(SS / 32, DD / 32, BB), dim3(32, 8), 0, stream>>>(qkvb, vT);

    // 4. scores[b] = q k^T / sqrt(d)  (per-batch M=N=2048, K=512) -> fp32
    gemm_bt<false><<<dim3(SS / 64, SS / 64, BB), 256, 0, stream>>>(
        qkvb /*q at col 0*/, qkvb + 512 /*k*/, nullptr, scor,
        DD, ND3, ND3, SS,
        (long)SS * ND3, (long)SS * ND3, (long)SS * SS,
        0.044194173824159216f /* 1/sqrt(512) */);

    // 5. softmax rows -> bf16 probs
    softmax_rows<<<MM, 256, 0, stream>>>(scor, probs);

    // 6. ctx[b] = probs[b] v[b]  (M=2048, N=512, K=2048) -> bf16
    gemm_bt<true><<<dim3(DD / 64, SS / 64, BB), 256, 0, stream>>>(
        probs, vT, nullptr, ctxb, SS, SS, SS, DD,
        (long)SS * SS, (long)DD * SS, (long)SS * DD, 1.0f);

    // 7. out = ctx Wo^T + bo  (M=8192, N=2048, K=512) -> fp32
    gemm_bt<false><<<dim3(CC / 64, MM / 64, 1), 256, 0, stream>>>(
        ctxb, wob, bo, out, DD, DD, DD, CC, 0, 0, 0, 1.0f);

    (void)in_sizes; (void)n_in; (void)out_size; (void)ws_size;
}

// Round 2
// 379.509 us; speedup vs baseline: 1.1134x; 1.1134x over previous
//
#include <hip/hip_runtime.h>
#include <math.h>

// ---------------------------------------------------------------------------
// SingleHeadSelfAttention: B=4, S=2048, C=2048, d=512
// R2: 128x128-tile MFMA GEMM with global_load_lds width=16 (m97 structure).
// ---------------------------------------------------------------------------

typedef __bf16 bf16;
typedef bf16 bf16x8 __attribute__((ext_vector_type(8)));
typedef bf16 bf16x4 __attribute__((ext_vector_type(4)));
typedef float f32x4 __attribute__((ext_vector_type(4)));

#define BB 4
#define SS 2048
#define CC 2048
#define DD 512
#define ND3 1536          // 3*DD
#define MM 8192           // BB*SS

typedef const __attribute__((address_space(1))) unsigned int g_u32;
typedef __attribute__((address_space(3))) unsigned int l_u32;

// async global->LDS, 16B per lane; lds base must be wave-uniform.
__device__ __forceinline__ void gl_lds16(const bf16* g, bf16* l) {
    __builtin_amdgcn_global_load_lds((g_u32*)g, (l_u32*)l, 16, 0, 0);
}

// ---------------- fp32 -> bf16 conversion (vectorized, grid-stride) --------
__global__ __launch_bounds__(256) void cvt_f32_bf16(const float* __restrict__ in,
                                                    bf16* __restrict__ out, int n4) {
    int i = blockIdx.x * 256 + threadIdx.x;
    int stride = gridDim.x * 256;
    for (; i < n4; i += stride) {
        float4 v = ((const float4*)in)[i];
        bf16x4 o;
        o[0] = (bf16)v.x; o[1] = (bf16)v.y; o[2] = (bf16)v.z; o[3] = (bf16)v.w;
        ((bf16x4*)out)[i] = o;
    }
}

// ---------------- transpose v: qkv[b][j][1024+d] -> vT[b][d][j] ------------
__global__ void transpose_v(const bf16* __restrict__ qkv, bf16* __restrict__ vT) {
    __shared__ bf16 tile[32][33];
    int b = blockIdx.z;
    int j0 = blockIdx.x * 32, d0 = blockIdx.y * 32;
    const bf16* src = qkv + (size_t)b * SS * ND3 + 1024;
#pragma unroll
    for (int i = 0; i < 4; i++) {
        int j = j0 + threadIdx.y + i * 8;
        tile[threadIdx.y + i * 8][threadIdx.x] = src[(size_t)j * ND3 + d0 + threadIdx.x];
    }
    __syncthreads();
    bf16* dst = vT + (size_t)b * DD * SS;
#pragma unroll
    for (int i = 0; i < 4; i++) {
        int dd = d0 + threadIdx.y + i * 8;
        dst[(size_t)dd * SS + j0 + threadIdx.x] = tile[threadIdx.x][threadIdx.y + i * 8];
    }
}

// ---------------- row softmax: fp32 scores (2048 cols) -> bf16 probs -------
__global__ __launch_bounds__(256) void softmax_rows(const float* __restrict__ S,
                                                    bf16* __restrict__ P) {
    const int row = blockIdx.x;
    const float* src = S + (size_t)row * SS;
    bf16* dst = P + (size_t)row * SS;
    const int t = threadIdx.x;
    float4 v0 = ((const float4*)src)[t];
    float4 v1 = ((const float4*)src)[t + 256];
    float mx = fmaxf(fmaxf(fmaxf(v0.x, v0.y), fmaxf(v0.z, v0.w)),
                     fmaxf(fmaxf(v1.x, v1.y), fmaxf(v1.z, v1.w)));
#pragma unroll
    for (int off = 32; off; off >>= 1) mx = fmaxf(mx, __shfl_xor(mx, off, 64));
    __shared__ float redm[4], reds[4];
    if ((t & 63) == 0) redm[t >> 6] = mx;
    __syncthreads();
    mx = fmaxf(fmaxf(redm[0], redm[1]), fmaxf(redm[2], redm[3]));
    float e[8];
    e[0] = __expf(v0.x - mx); e[1] = __expf(v0.y - mx);
    e[2] = __expf(v0.z - mx); e[3] = __expf(v0.w - mx);
    e[4] = __expf(v1.x - mx); e[5] = __expf(v1.y - mx);
    e[6] = __expf(v1.z - mx); e[7] = __expf(v1.w - mx);
    float s = ((e[0] + e[1]) + (e[2] + e[3])) + ((e[4] + e[5]) + (e[6] + e[7]));
#pragma unroll
    for (int off = 32; off; off >>= 1) s += __shfl_xor(s, off, 64);
    if ((t & 63) == 0) reds[t >> 6] = s;
    __syncthreads();
    s = (reds[0] + reds[1]) + (reds[2] + reds[3]);
    float inv = 1.0f / s;
    bf16x4 o0, o1;
    o0[0] = (bf16)(e[0] * inv); o0[1] = (bf16)(e[1] * inv);
    o0[2] = (bf16)(e[2] * inv); o0[3] = (bf16)(e[3] * inv);
    o1[0] = (bf16)(e[4] * inv); o1[1] = (bf16)(e[5] * inv);
    o1[2] = (bf16)(e[6] * inv); o1[3] = (bf16)(e[7] * inv);
    ((bf16x4*)dst)[t] = o0;
    ((bf16x4*)dst)[t + 256] = o1;
}

// ---------------- C[m][n] = scale * sum_k A[m][k]B[n][k] + bias[n] ---------
// 128x128 tile, BK=32, 4 waves each computing 64x64 via 4x4 MFMA 16x16x32.
// Staging via global_load_lds_dwordx4: LDS tiles UNPADDED [128][32] bf16.
template <bool OUT_BF16>
__global__ __launch_bounds__(256) void gemm_bt(const bf16* __restrict__ A,
                                               const bf16* __restrict__ Bm,
                                               const float* __restrict__ bias,
                                               void* __restrict__ Cv,
                                               int K, int lda, int ldb, int ldc,
                                               long ab, long bb, long cb,
                                               float scale) {
    __shared__ bf16 As[128 * 32];
    __shared__ bf16 Bs[128 * 32];
    A += (size_t)blockIdx.z * ab;
    Bm += (size_t)blockIdx.z * bb;
    const int m0 = blockIdx.y * 128, n0 = blockIdx.x * 128;
    const int t = threadIdx.x, lane = t & 63, w = t >> 6;
    const int wm = (w >> 1) * 64, wn = (w & 1) * 64;   // wave's 64x64 sub-tile
    const int q = lane >> 4, cl = lane & 15;
    // staging geometry: wave w instr j covers rows [j*64 + w*16, +16), 32 cols
    const int srow = lane >> 2;        // 0..15 within 16-row chunk
    const int scol = (lane & 3) * 8;   // 0,8,16,24
    const bf16* pa0 = A + (size_t)(m0 + w * 16 + srow) * lda + scol;
    const bf16* pa1 = pa0 + (size_t)64 * lda;
    const bf16* pb0 = Bm + (size_t)(n0 + w * 16 + srow) * ldb + scol;
    const bf16* pb1 = pb0 + (size_t)64 * ldb;
    bf16* lA0 = As + (w * 16) * 32;
    bf16* lA1 = As + (64 + w * 16) * 32;
    bf16* lB0 = Bs + (w * 16) * 32;
    bf16* lB1 = Bs + (64 + w * 16) * 32;

    f32x4 acc[4][4] = {};
    for (int k0 = 0; k0 < K; k0 += 32) {
        gl_lds16(pa0 + k0, lA0);
        gl_lds16(pa1 + k0, lA1);
        gl_lds16(pb0 + k0, lB0);
        gl_lds16(pb1 + k0, lB1);
        __syncthreads();   // drains vmcnt(0) + barrier: LDS tiles ready
        bf16x8 af[4], bfr[4];
#pragma unroll
        for (int i = 0; i < 4; i++)
            af[i] = *(const bf16x8*)&As[(wm + i * 16 + cl) * 32 + q * 8];
#pragma unroll
        for (int j = 0; j < 4; j++)
            bfr[j] = *(const bf16x8*)&Bs[(wn + j * 16 + cl) * 32 + q * 8];
#pragma unroll
        for (int i = 0; i < 4; i++)
#pragma unroll
            for (int j = 0; j < 4; j++)
                acc[i][j] = __builtin_amdgcn_mfma_f32_16x16x32_bf16(af[i], bfr[j], acc[i][j], 0, 0, 0);
        __syncthreads();   // protect LDS before next staging
    }
#pragma unroll
    for (int i = 0; i < 4; i++)
#pragma unroll
        for (int j = 0; j < 4; j++) {
            int col = n0 + wn + j * 16 + cl;
            float bvv = bias ? bias[col] : 0.0f;
#pragma unroll
            for (int r = 0; r < 4; r++) {
                int row = m0 + wm + i * 16 + q * 4 + r;
                float val = acc[i][j][r] * scale + bvv;
                if (OUT_BF16)
                    ((bf16*)Cv)[(size_t)blockIdx.z * cb + (size_t)row * ldc + col] = (bf16)val;
                else
                    ((float*)Cv)[(size_t)blockIdx.z * cb + (size_t)row * ldc + col] = val;
            }
        }
}

// ---------------------------------------------------------------------------
extern "C" void kernel_launch(void* const* d_in, const int* in_sizes, int n_in,
                              void* d_out, int out_size, void* d_ws, size_t ws_size,
                              hipStream_t stream) {
    const float* x    = (const float*)d_in[0];  // (4,2048,2048)
    const float* Wqkv = (const float*)d_in[1];  // (1536,2048)
    const float* bqkv = (const float*)d_in[2];  // (1536,)
    const float* Wo   = (const float*)d_in[3];  // (2048,512)
    const float* bo   = (const float*)d_in[4];  // (2048,)
    float* out = (float*)d_out;                 // (4,2048,2048) fp32

    char* ws = (char*)d_ws;
    size_t off = 0;
    bf16* xb    = (bf16*)(ws + off); off += (size_t)MM * CC * 2;       // 32 MB
    bf16* wqkvb = (bf16*)(ws + off); off += (size_t)ND3 * CC * 2;      // 6 MB
    bf16* wob   = (bf16*)(ws + off); off += (size_t)CC * DD * 2;       // 2 MB
    bf16* qkvb  = (bf16*)(ws + off); off += (size_t)MM * ND3 * 2;      // 24 MB
    bf16* vT    = (bf16*)(ws + off); off += (size_t)BB * DD * SS * 2;  // 8 MB
    float* scor = (float*)(ws + off); off += (size_t)BB * SS * SS * 4; // 64 MB
    bf16* probs = (bf16*)(ws + off); off += (size_t)BB * SS * SS * 2;  // 32 MB
    bf16* ctxb  = (bf16*)(ws + off); off += (size_t)MM * DD * 2;       // 8 MB

    // 1. convert inputs to bf16
    cvt_f32_bf16<<<4096, 256, 0, stream>>>(x, xb, MM * CC / 4);
    cvt_f32_bf16<<<1024, 256, 0, stream>>>(Wqkv, wqkvb, ND3 * CC / 4);
    cvt_f32_bf16<<<512, 256, 0, stream>>>(Wo, wob, CC * DD / 4);

    // 2. qkv = x Wqkv^T + bqkv   (M=8192, N=1536, K=2048) -> bf16
    gemm_bt<true><<<dim3(ND3 / 128, MM / 128, 1), 256, 0, stream>>>(
        xb, wqkvb, bqkv, qkvb, CC, CC, CC, ND3, 0, 0, 0, 1.0f);

    // 3. vT[b][d][j] = v[b][j][d]
    transpose_v<<<dim3(SS / 32, DD / 32, BB), dim3(32, 8), 0, stream>>>(qkvb, vT);

    // 4. scores[b] = q k^T / sqrt(d)  (per-batch M=N=2048, K=512) -> fp32
    gemm_bt<false><<<dim3(SS / 128, SS / 128, BB), 256, 0, stream>>>(
        qkvb /*q*/, qkvb + 512 /*k*/, nullptr, scor,
        DD, ND3, ND3, SS,
        (long)SS * ND3, (long)SS * ND3, (long)SS * SS,
        0.044194173824159216f /* 1/sqrt(512) */);

    // 5. softmax rows -> bf16 probs
    softmax_rows<<<MM, 256, 0, stream>>>(scor, probs);

    // 6. ctx[b] = probs[b] v[b]  (M=2048, N=512, K=2048) -> bf16
    gemm_bt<true><<<dim3(DD / 128, SS / 128, BB), 256, 0, stream>>>(
        probs, vT, nullptr, ctxb, SS, SS, SS, DD,
        (long)SS * SS, (long)DD * SS, (long)SS * DD, 1.0f);

    // 7. out = ctx Wo^T + bo  (M=8192, N=2048, K=512) -> fp32
    gemm_bt<false><<<dim3(CC / 128, MM / 128, 1), 256, 0, stream>>>(
        ctxb, wob, bo, out, DD, DD, DD, CC, 0, 0, 0, 1.0f);

    (void)in_sizes; (void)n_in; (void)out_size; (void)ws_size;
}

// Round 3
// 343.606 us; speedup vs baseline: 1.2297x; 1.1045x over previous
//
#include <hip/hip_runtime.h>
#include <math.h>

// ---------------------------------------------------------------------------
// SingleHeadSelfAttention: B=4, S=2048, C=2048, d=512
// R3: fused exp into scores epilogue (+rowsum atomics), PV divides by rowsum;
//     PV uses 128x64 tiles for 2 blocks/CU. No separate softmax pass.
// ---------------------------------------------------------------------------

typedef __bf16 bf16;
typedef bf16 bf16x8 __attribute__((ext_vector_type(8)));
typedef bf16 bf16x4 __attribute__((ext_vector_type(4)));
typedef float f32x4 __attribute__((ext_vector_type(4)));

#define BB 4
#define SS 2048
#define CC 2048
#define DD 512
#define ND3 1536          // 3*DD
#define MM 8192           // BB*SS

typedef const __attribute__((address_space(1))) unsigned int g_u32;
typedef __attribute__((address_space(3))) unsigned int l_u32;

__device__ __forceinline__ void gl_lds16(const bf16* g, bf16* l) {
    __builtin_amdgcn_global_load_lds((g_u32*)g, (l_u32*)l, 16, 0, 0);
}

// ---------------- fp32 -> bf16 conversion (vectorized, grid-stride) --------
__global__ __launch_bounds__(256) void cvt_f32_bf16(const float* __restrict__ in,
                                                    bf16* __restrict__ out, int n4) {
    int i = blockIdx.x * 256 + threadIdx.x;
    int stride = gridDim.x * 256;
    for (; i < n4; i += stride) {
        float4 v = ((const float4*)in)[i];
        bf16x4 o;
        o[0] = (bf16)v.x; o[1] = (bf16)v.y; o[2] = (bf16)v.z; o[3] = (bf16)v.w;
        ((bf16x4*)out)[i] = o;
    }
}

// ---------------- transpose v: qkv[b][j][1024+d] -> vT[b][d][j] ------------
__global__ void transpose_v(const bf16* __restrict__ qkv, bf16* __restrict__ vT) {
    __shared__ bf16 tile[32][33];
    int b = blockIdx.z;
    int j0 = blockIdx.x * 32, d0 = blockIdx.y * 32;
    const bf16* src = qkv + (size_t)b * SS * ND3 + 1024;
#pragma unroll
    for (int i = 0; i < 4; i++) {
        int j = j0 + threadIdx.y + i * 8;
        tile[threadIdx.y + i * 8][threadIdx.x] = src[(size_t)j * ND3 + d0 + threadIdx.x];
    }
    __syncthreads();
    bf16* dst = vT + (size_t)b * DD * SS;
#pragma unroll
    for (int i = 0; i < 4; i++) {
        int dd = d0 + threadIdx.y + i * 8;
        dst[(size_t)dd * SS + j0 + threadIdx.x] = tile[threadIdx.x][threadIdx.y + i * 8];
    }
}

// ---------------- C[m][n] = f( scale * sum_k A[m][k]B[n][k] ) --------------
// BM=128 fixed. BN=128: 4 waves in 2x2, each 64x64 (4x4 MFMA tiles).
//                BN=64 : 4 waves in 4x1, each 32x64 (2x4 MFMA tiles).
// Staging via global_load_lds width=16; LDS tiles unpadded [rows][32] bf16.
// EPI: 0 = scale*acc + bias[col]
//      1 = exp(scale*acc), bf16 store, atomicAdd row sums into rowsum[]
//      2 = acc / rowsum[global row]
template <bool OUT_BF16, int BN, int EPI>
__global__ __launch_bounds__(256) void gemm_bt(const bf16* __restrict__ A,
                                               const bf16* __restrict__ Bm,
                                               const float* __restrict__ bias,
                                               float* __restrict__ rowsum,
                                               void* __restrict__ Cv,
                                               int K, int lda, int ldb, int ldc,
                                               long ab, long bb, long cb,
                                               float scale) {
    constexpr int TM = (BN == 128) ? 4 : 2;     // MFMA tile-rows per wave
    __shared__ bf16 As[128 * 32];
    __shared__ bf16 Bs[BN * 32];
    A += (size_t)blockIdx.z * ab;
    Bm += (size_t)blockIdx.z * bb;
    const int m0 = blockIdx.y * 128, n0 = blockIdx.x * BN;
    const int t = threadIdx.x, lane = t & 63, w = t >> 6;
    const int wm = (BN == 128) ? (w >> 1) * 64 : w * 32;
    const int wn = (BN == 128) ? (w & 1) * 64 : 0;
    const int q = lane >> 4, cl = lane & 15;
    // staging geometry: wave w covers rows [chunk*64 + w*16, +16), 32 cols
    const int srow = lane >> 2;        // 0..15
    const int scol = (lane & 3) * 8;   // 0,8,16,24
    const bf16* pa0 = A + (size_t)(m0 + w * 16 + srow) * lda + scol;
    const bf16* pa1 = pa0 + (size_t)64 * lda;
    const bf16* pb0 = Bm + (size_t)(n0 + w * 16 + srow) * ldb + scol;
    const bf16* pb1 = pb0 + (size_t)64 * ldb;
    bf16* lA0 = As + (w * 16) * 32;
    bf16* lA1 = As + (64 + w * 16) * 32;
    bf16* lB0 = Bs + (w * 16) * 32;
    bf16* lB1 = Bs + (64 + w * 16) * 32;

    f32x4 acc[TM][4] = {};
    for (int k0 = 0; k0 < K; k0 += 32) {
        gl_lds16(pa0 + k0, lA0);
        gl_lds16(pa1 + k0, lA1);
        gl_lds16(pb0 + k0, lB0);
        if constexpr (BN == 128) gl_lds16(pb1 + k0, lB1);
        __syncthreads();
        bf16x8 af[TM], bfr[4];
#pragma unroll
        for (int i = 0; i < TM; i++)
            af[i] = *(const bf16x8*)&As[(wm + i * 16 + cl) * 32 + q * 8];
#pragma unroll
        for (int j = 0; j < 4; j++)
            bfr[j] = *(const bf16x8*)&Bs[(wn + j * 16 + cl) * 32 + q * 8];
#pragma unroll
        for (int i = 0; i < TM; i++)
#pragma unroll
            for (int j = 0; j < 4; j++)
                acc[i][j] = __builtin_amdgcn_mfma_f32_16x16x32_bf16(af[i], bfr[j], acc[i][j], 0, 0, 0);
        __syncthreads();
    }

#pragma unroll
    for (int i = 0; i < TM; i++) {
        float inv[4];
        if constexpr (EPI == 2) {
#pragma unroll
            for (int r = 0; r < 4; r++)
                inv[r] = 1.0f / rowsum[(size_t)blockIdx.z * SS + m0 + wm + i * 16 + q * 4 + r];
        }
        float rp[4] = {0.f, 0.f, 0.f, 0.f};
#pragma unroll
        for (int j = 0; j < 4; j++) {
            int col = n0 + wn + j * 16 + cl;
            float bvv = (EPI == 0 && bias) ? bias[col] : 0.0f;
#pragma unroll
            for (int r = 0; r < 4; r++) {
                int row = m0 + wm + i * 16 + q * 4 + r;
                float val;
                if constexpr (EPI == 1) { val = __expf(acc[i][j][r] * scale); rp[r] += val; }
                else if constexpr (EPI == 2) { val = acc[i][j][r] * inv[r]; }
                else { val = acc[i][j][r] * scale + bvv; }
                if (OUT_BF16)
                    ((bf16*)Cv)[(size_t)blockIdx.z * cb + (size_t)row * ldc + col] = (bf16)val;
                else
                    ((float*)Cv)[(size_t)blockIdx.z * cb + (size_t)row * ldc + col] = val;
            }
        }
        if constexpr (EPI == 1) {
            // reduce partial row sums over the 16 'cl' lanes, then one atomic
#pragma unroll
            for (int r = 0; r < 4; r++) {
#pragma unroll
                for (int off = 1; off < 16; off <<= 1)
                    rp[r] += __shfl_xor(rp[r], off, 64);
            }
            if (cl == 0) {
#pragma unroll
                for (int r = 0; r < 4; r++)
                    atomicAdd(&rowsum[(size_t)blockIdx.z * SS + m0 + wm + i * 16 + q * 4 + r], rp[r]);
            }
        }
    }
}

// ---------------------------------------------------------------------------
extern "C" void kernel_launch(void* const* d_in, const int* in_sizes, int n_in,
                              void* d_out, int out_size, void* d_ws, size_t ws_size,
                              hipStream_t stream) {
    const float* x    = (const float*)d_in[0];  // (4,2048,2048)
    const float* Wqkv = (const float*)d_in[1];  // (1536,2048)
    const float* bqkv = (const float*)d_in[2];  // (1536,)
    const float* Wo   = (const float*)d_in[3];  // (2048,512)
    const float* bo   = (const float*)d_in[4];  // (2048,)
    float* out = (float*)d_out;                 // (4,2048,2048) fp32

    char* ws = (char*)d_ws;
    size_t off = 0;
    bf16* xb    = (bf16*)(ws + off); off += (size_t)MM * CC * 2;       // 32 MB
    bf16* wqkvb = (bf16*)(ws + off); off += (size_t)ND3 * CC * 2;      // 6 MB
    bf16* wob   = (bf16*)(ws + off); off += (size_t)CC * DD * 2;       // 2 MB
    bf16* qkvb  = (bf16*)(ws + off); off += (size_t)MM * ND3 * 2;      // 24 MB
    bf16* vT    = (bf16*)(ws + off); off += (size_t)BB * DD * SS * 2;  // 8 MB
    bf16* expS  = (bf16*)(ws + off); off += (size_t)BB * SS * SS * 2;  // 32 MB
    bf16* ctxb  = (bf16*)(ws + off); off += (size_t)MM * DD * 2;       // 8 MB
    float* rsum = (float*)(ws + off); off += (size_t)MM * 4;           // 32 KB

    // 0. zero row-sum accumulator (ws is poisoned before every launch)
    hipMemsetAsync(rsum, 0, (size_t)MM * 4, stream);

    // 1. convert inputs to bf16
    cvt_f32_bf16<<<4096, 256, 0, stream>>>(x, xb, MM * CC / 4);
    cvt_f32_bf16<<<1024, 256, 0, stream>>>(Wqkv, wqkvb, ND3 * CC / 4);
    cvt_f32_bf16<<<512, 256, 0, stream>>>(Wo, wob, CC * DD / 4);

    // 2. qkv = x Wqkv^T + bqkv   (M=8192, N=1536, K=2048) -> bf16
    gemm_bt<true, 128, 0><<<dim3(ND3 / 128, MM / 128, 1), 256, 0, stream>>>(
        xb, wqkvb, bqkv, nullptr, qkvb, CC, CC, CC, ND3, 0, 0, 0, 1.0f);

    // 3. vT[b][d][j] = v[b][j][d]
    transpose_v<<<dim3(SS / 32, DD / 32, BB), dim3(32, 8), 0, stream>>>(qkvb, vT);

    // 4. expS[b] = exp(q k^T / sqrt(d)), rowsum accumulated  -> bf16
    gemm_bt<true, 128, 1><<<dim3(SS / 128, SS / 128, BB), 256, 0, stream>>>(
        qkvb /*q*/, qkvb + 512 /*k*/, nullptr, rsum, expS,
        DD, ND3, ND3, SS,
        (long)SS * ND3, (long)SS * ND3, (long)SS * SS,
        0.044194173824159216f /* 1/sqrt(512) */);

    // 5. ctx[b] = (expS[b] v[b]) / rowsum  (M=2048, N=512, K=2048) -> bf16
    gemm_bt<true, 64, 2><<<dim3(DD / 64, SS / 128, BB), 256, 0, stream>>>(
        expS, vT, nullptr, rsum, ctxb, SS, SS, SS, DD,
        (long)SS * SS, (long)DD * SS, (long)SS * DD, 1.0f);

    // 6. out = ctx Wo^T + bo  (M=8192, N=2048, K=512) -> fp32
    gemm_bt<false, 128, 0><<<dim3(CC / 128, MM / 128, 1), 256, 0, stream>>>(
        ctxb, wob, bo, nullptr, out, DD, DD, DD, CC, 0, 0, 0, 1.0f);

    (void)in_sizes; (void)n_in; (void)out_size; (void)ws_size;
}

// Round 4
// 336.214 us; speedup vs baseline: 1.2567x; 1.0220x over previous
//
#include <hip/hip_runtime.h>
#include <math.h>

// ---------------------------------------------------------------------------
// SingleHeadSelfAttention: B=4, S=2048, C=2048, d=512
// R4: dispatch fusion. prep = (cvt x, Wqkv, Wo -> bf16) + rsum zero in one
//     kernel; QKV GEMM epilogue writes v directly transposed (vT) -> no
//     transpose kernel. 9 dispatches -> 5.
// ---------------------------------------------------------------------------

typedef __bf16 bf16;
typedef bf16 bf16x8 __attribute__((ext_vector_type(8)));
typedef bf16 bf16x4 __attribute__((ext_vector_type(4)));
typedef float f32x4 __attribute__((ext_vector_type(4)));

#define BB 4
#define SS 2048
#define CC 2048
#define DD 512
#define ND3 1536          // 3*DD
#define MM 8192           // BB*SS

typedef const __attribute__((address_space(1))) unsigned int g_u32;
typedef __attribute__((address_space(3))) unsigned int l_u32;

__device__ __forceinline__ void gl_lds16(const bf16* g, bf16* l) {
    __builtin_amdgcn_global_load_lds((g_u32*)g, (l_u32*)l, 16, 0, 0);
}

// ---------------- prep: fp32->bf16 for x/Wqkv/Wo + zero rsum ---------------
#define N4_X   (MM * CC / 4)          // 4194304
#define N4_WQ  (ND3 * CC / 4)         //  786432
#define N4_WO  (CC * DD / 4)          //  262144
#define N4_RS  (MM / 4)               //    2048
#define N4_TOT (N4_X + N4_WQ + N4_WO + N4_RS)

__global__ __launch_bounds__(256) void prep(const float* __restrict__ x,
                                            const float* __restrict__ Wqkv,
                                            const float* __restrict__ Wo,
                                            bf16* __restrict__ xb,
                                            bf16* __restrict__ wqkvb,
                                            bf16* __restrict__ wob,
                                            float* __restrict__ rsum) {
    int i = blockIdx.x * 256 + threadIdx.x;
    const int stride = gridDim.x * 256;
    for (; i < N4_TOT; i += stride) {
        if (i < N4_X + N4_WQ + N4_WO) {
            const float* src; bf16* dst; int j = i;
            if (j < N4_X)                { src = x;    dst = xb; }
            else if (j < N4_X + N4_WQ)   { src = Wqkv; dst = wqkvb; j -= N4_X; }
            else                         { src = Wo;   dst = wob;   j -= N4_X + N4_WQ; }
            float4 v = ((const float4*)src)[j];
            bf16x4 o;
            o[0] = (bf16)v.x; o[1] = (bf16)v.y; o[2] = (bf16)v.z; o[3] = (bf16)v.w;
            ((bf16x4*)dst)[j] = o;
        } else {
            int j = i - (N4_X + N4_WQ + N4_WO);
            ((float4*)rsum)[j] = float4{0.f, 0.f, 0.f, 0.f};
        }
    }
}

// ---------------- C[m][n] = f( scale * sum_k A[m][k]B[n][k] ) --------------
// BM=128 fixed. BN=128: 4 waves in 2x2, each 64x64 (4x4 MFMA tiles).
//                BN=64 : 4 waves in 4x1, each 32x64 (2x4 MFMA tiles).
// Staging via global_load_lds width=16; LDS tiles unpadded [rows][32] bf16.
// EPI: 0 = scale*acc + bias[col]
//      1 = exp(scale*acc), bf16 store, atomicAdd row sums into rowsum[]
//      2 = acc / rowsum[global row]
//      3 = QKV split: col<1024 -> acc+bias[col] into C; col>=1024 ->
//          acc+bias[col] transposed into vT[b][col-1024][s] (b=row>>11)
template <bool OUT_BF16, int BN, int EPI>
__global__ __launch_bounds__(256) void gemm_bt(const bf16* __restrict__ A,
                                               const bf16* __restrict__ Bm,
                                               const float* __restrict__ bias,
                                               float* __restrict__ rowsum,
                                               bf16* __restrict__ vTp,
                                               void* __restrict__ Cv,
                                               int K, int lda, int ldb, int ldc,
                                               long ab, long bb, long cb,
                                               float scale) {
    constexpr int TM = (BN == 128) ? 4 : 2;     // MFMA tile-rows per wave
    __shared__ bf16 As[128 * 32];
    __shared__ bf16 Bs[BN * 32];
    A += (size_t)blockIdx.z * ab;
    Bm += (size_t)blockIdx.z * bb;
    const int m0 = blockIdx.y * 128, n0 = blockIdx.x * BN;
    const int t = threadIdx.x, lane = t & 63, w = t >> 6;
    const int wm = (BN == 128) ? (w >> 1) * 64 : w * 32;
    const int wn = (BN == 128) ? (w & 1) * 64 : 0;
    const int q = lane >> 4, cl = lane & 15;
    // staging geometry: wave w covers rows [chunk*64 + w*16, +16), 32 cols
    const int srow = lane >> 2;        // 0..15
    const int scol = (lane & 3) * 8;   // 0,8,16,24
    const bf16* pa0 = A + (size_t)(m0 + w * 16 + srow) * lda + scol;
    const bf16* pa1 = pa0 + (size_t)64 * lda;
    const bf16* pb0 = Bm + (size_t)(n0 + w * 16 + srow) * ldb + scol;
    const bf16* pb1 = pb0 + (size_t)64 * ldb;
    bf16* lA0 = As + (w * 16) * 32;
    bf16* lA1 = As + (64 + w * 16) * 32;
    bf16* lB0 = Bs + (w * 16) * 32;
    bf16* lB1 = Bs + (64 + w * 16) * 32;

    f32x4 acc[TM][4] = {};
    for (int k0 = 0; k0 < K; k0 += 32) {
        gl_lds16(pa0 + k0, lA0);
        gl_lds16(pa1 + k0, lA1);
        gl_lds16(pb0 + k0, lB0);
        if constexpr (BN == 128) gl_lds16(pb1 + k0, lB1);
        __syncthreads();
        bf16x8 af[TM], bfr[4];
#pragma unroll
        for (int i = 0; i < TM; i++)
            af[i] = *(const bf16x8*)&As[(wm + i * 16 + cl) * 32 + q * 8];
#pragma unroll
        for (int j = 0; j < 4; j++)
            bfr[j] = *(const bf16x8*)&Bs[(wn + j * 16 + cl) * 32 + q * 8];
#pragma unroll
        for (int i = 0; i < TM; i++)
#pragma unroll
            for (int j = 0; j < 4; j++)
                acc[i][j] = __builtin_amdgcn_mfma_f32_16x16x32_bf16(af[i], bfr[j], acc[i][j], 0, 0, 0);
        __syncthreads();
    }

    const bool v_block = (EPI == 3) && (n0 >= 1024);
#pragma unroll
    for (int i = 0; i < TM; i++) {
        float inv[4];
        if constexpr (EPI == 2) {
#pragma unroll
            for (int r = 0; r < 4; r++)
                inv[r] = 1.0f / rowsum[(size_t)blockIdx.z * SS + m0 + wm + i * 16 + q * 4 + r];
        }
        float rp[4] = {0.f, 0.f, 0.f, 0.f};
#pragma unroll
        for (int j = 0; j < 4; j++) {
            int col = n0 + wn + j * 16 + cl;
            float bvv = ((EPI == 0 || EPI == 3) && bias) ? bias[col] : 0.0f;
            if (v_block) {
                // rows m0+wm+i*16+q*4 .. +3 are consecutive s -> pack b64
                int row = m0 + wm + i * 16 + q * 4;
                int b = row >> 11, s = row & 2047;
                bf16x4 o;
#pragma unroll
                for (int r = 0; r < 4; r++) o[r] = (bf16)(acc[i][j][r] * scale + bvv);
                *(bf16x4*)&vTp[((size_t)b * DD + (col - 1024)) * SS + s] = o;
            } else {
#pragma unroll
                for (int r = 0; r < 4; r++) {
                    int row = m0 + wm + i * 16 + q * 4 + r;
                    float val;
                    if constexpr (EPI == 1) { val = __expf(acc[i][j][r] * scale); rp[r] += val; }
                    else if constexpr (EPI == 2) { val = acc[i][j][r] * inv[r]; }
                    else { val = acc[i][j][r] * scale + bvv; }
                    if (OUT_BF16)
                        ((bf16*)Cv)[(size_t)blockIdx.z * cb + (size_t)row * ldc + col] = (bf16)val;
                    else
                        ((float*)Cv)[(size_t)blockIdx.z * cb + (size_t)row * ldc + col] = val;
                }
            }
        }
        if constexpr (EPI == 1) {
            // reduce partial row sums over the 16 'cl' lanes, then one atomic
#pragma unroll
            for (int r = 0; r < 4; r++) {
#pragma unroll
                for (int off = 1; off < 16; off <<= 1)
                    rp[r] += __shfl_xor(rp[r], off, 64);
            }
            if (cl == 0) {
#pragma unroll
                for (int r = 0; r < 4; r++)
                    atomicAdd(&rowsum[(size_t)blockIdx.z * SS + m0 + wm + i * 16 + q * 4 + r], rp[r]);
            }
        }
    }
}

// ---------------------------------------------------------------------------
extern "C" void kernel_launch(void* const* d_in, const int* in_sizes, int n_in,
                              void* d_out, int out_size, void* d_ws, size_t ws_size,
                              hipStream_t stream) {
    const float* x    = (const float*)d_in[0];  // (4,2048,2048)
    const float* Wqkv = (const float*)d_in[1];  // (1536,2048)
    const float* bqkv = (const float*)d_in[2];  // (1536,)
    const float* Wo   = (const float*)d_in[3];  // (2048,512)
    const float* bo   = (const float*)d_in[4];  // (2048,)
    float* out = (float*)d_out;                 // (4,2048,2048) fp32

    char* ws = (char*)d_ws;
    size_t off = 0;
    bf16* xb    = (bf16*)(ws + off); off += (size_t)MM * CC * 2;       // 32 MB
    bf16* wqkvb = (bf16*)(ws + off); off += (size_t)ND3 * CC * 2;      // 6 MB
    bf16* wob   = (bf16*)(ws + off); off += (size_t)CC * DD * 2;       // 2 MB
    bf16* qkvb  = (bf16*)(ws + off); off += (size_t)MM * ND3 * 2;      // 24 MB (v-third unused)
    bf16* vT    = (bf16*)(ws + off); off += (size_t)BB * DD * SS * 2;  // 8 MB
    bf16* expS  = (bf16*)(ws + off); off += (size_t)BB * SS * SS * 2;  // 32 MB
    bf16* ctxb  = (bf16*)(ws + off); off += (size_t)MM * DD * 2;       // 8 MB
    float* rsum = (float*)(ws + off); off += (size_t)MM * 4;           // 32 KB

    // 1. convert inputs to bf16 + zero rsum (one kernel)
    prep<<<2048, 256, 0, stream>>>(x, Wqkv, Wo, xb, wqkvb, wob, rsum);

    // 2. qkv = x Wqkv^T + bqkv; q,k -> qkvb rows, v -> vT transposed
    gemm_bt<true, 128, 3><<<dim3(ND3 / 128, MM / 128, 1), 256, 0, stream>>>(
        xb, wqkvb, bqkv, nullptr, vT, qkvb, CC, CC, CC, ND3, 0, 0, 0, 1.0f);

    // 3. expS[b] = exp(q k^T / sqrt(d)), rowsum accumulated  -> bf16
    gemm_bt<true, 128, 1><<<dim3(SS / 128, SS / 128, BB), 256, 0, stream>>>(
        qkvb /*q*/, qkvb + 512 /*k*/, nullptr, rsum, nullptr, expS,
        DD, ND3, ND3, SS,
        (long)SS * ND3, (long)SS * ND3, (long)SS * SS,
        0.044194173824159216f /* 1/sqrt(512) */);

    // 4. ctx[b] = (expS[b] v[b]) / rowsum  (M=2048, N=512, K=2048) -> bf16
    gemm_bt<true, 64, 2><<<dim3(DD / 64, SS / 128, BB), 256, 0, stream>>>(
        expS, vT, nullptr, rsum, nullptr, ctxb, SS, SS, SS, DD,
        (long)SS * SS, (long)DD * SS, (long)SS * DD, 1.0f);

    // 5. out = ctx Wo^T + bo  (M=8192, N=2048, K=512) -> fp32
    gemm_bt<false, 128, 0><<<dim3(CC / 128, MM / 128, 1), 256, 0, stream>>>(
        ctxb, wob, bo, nullptr, nullptr, out, DD, DD, DD, CC, 0, 0, 0, 1.0f);

    (void)in_sizes; (void)n_in; (void)out_size; (void)ws_size;
}

// Round 5
// 331.983 us; speedup vs baseline: 1.2727x; 1.0127x over previous
//
#include <hip/hip_runtime.h>
#include <math.h>

// ---------------------------------------------------------------------------
// SingleHeadSelfAttention: B=4, S=2048, C=2048, d=512
// R5: transposed-output epilogues with packed b64 stores.
//   scores: S^T = k q^T, exp, packed store into expS[q][k], column-sum atomics
//   PV:     ctx^T = vT expS^T (A=vT,B=expS), /rowsum[col], packed into ctx[q][d]
// ---------------------------------------------------------------------------

typedef __bf16 bf16;
typedef bf16 bf16x8 __attribute__((ext_vector_type(8)));
typedef bf16 bf16x4 __attribute__((ext_vector_type(4)));
typedef float f32x4 __attribute__((ext_vector_type(4)));

#define BB 4
#define SS 2048
#define CC 2048
#define DD 512
#define ND3 1536          // 3*DD
#define MM 8192           // BB*SS

typedef const __attribute__((address_space(1))) unsigned int g_u32;
typedef __attribute__((address_space(3))) unsigned int l_u32;

__device__ __forceinline__ void gl_lds16(const bf16* g, bf16* l) {
    __builtin_amdgcn_global_load_lds((g_u32*)g, (l_u32*)l, 16, 0, 0);
}

// ---------------- prep: fp32->bf16 for x/Wqkv/Wo + zero rsum ---------------
#define N4_X   (MM * CC / 4)          // 4194304
#define N4_WQ  (ND3 * CC / 4)         //  786432
#define N4_WO  (CC * DD / 4)          //  262144
#define N4_RS  (MM / 4)               //    2048
#define N4_TOT (N4_X + N4_WQ + N4_WO + N4_RS)

__global__ __launch_bounds__(256) void prep(const float* __restrict__ x,
                                            const float* __restrict__ Wqkv,
                                            const float* __restrict__ Wo,
                                            bf16* __restrict__ xb,
                                            bf16* __restrict__ wqkvb,
                                            bf16* __restrict__ wob,
                                            float* __restrict__ rsum) {
    int i = blockIdx.x * 256 + threadIdx.x;
    const int stride = gridDim.x * 256;
    for (; i < N4_TOT; i += stride) {
        if (i < N4_X + N4_WQ + N4_WO) {
            const float* src; bf16* dst; int j = i;
            if (j < N4_X)                { src = x;    dst = xb; }
            else if (j < N4_X + N4_WQ)   { src = Wqkv; dst = wqkvb; j -= N4_X; }
            else                         { src = Wo;   dst = wob;   j -= N4_X + N4_WQ; }
            float4 v = ((const float4*)src)[j];
            bf16x4 o;
            o[0] = (bf16)v.x; o[1] = (bf16)v.y; o[2] = (bf16)v.z; o[3] = (bf16)v.w;
            ((bf16x4*)dst)[j] = o;
        } else {
            int j = i - (N4_X + N4_WQ + N4_WO);
            ((float4*)rsum)[j] = float4{0.f, 0.f, 0.f, 0.f};
        }
    }
}

// ---------------- C[m][n] = f( scale * sum_k A[m][k]B[n][k] ) --------------
// BM=128 fixed. BN=128: 4 waves in 2x2 (each 64x64, TM=4).
//                BN=64 : 4 waves in 4x1 (each 32x64, TM=2).
// Staging via global_load_lds width=16; LDS tiles unpadded [rows][32] bf16.
// EPI: 0 = scale*acc + bias[col], row-major scalar stores (fp32 or bf16)
//      3 = QKV split: col<1024 -> row-major C; col>=1024 -> transposed pack
//          into vT[b][col-1024][s]
//      4 = scoresT: exp(scale*acc), packed b64 store C^T[col][row..+3] into
//          Cv (ld ldc), column sums atomicAdd into rowsum[z*SS+col]
//      5 = pvT: acc * (1/rowsum[z*SS+col]), packed b64 store C^T[col][row..]
template <bool OUT_BF16, int BN, int EPI>
__global__ __launch_bounds__(256) void gemm_bt(const bf16* __restrict__ A,
                                               const bf16* __restrict__ Bm,
                                               const float* __restrict__ bias,
                                               float* __restrict__ rowsum,
                                               bf16* __restrict__ vTp,
                                               void* __restrict__ Cv,
                                               int K, int lda, int ldb, int ldc,
                                               long ab, long bb, long cb,
                                               float scale) {
    constexpr int TM = (BN == 128) ? 4 : 2;     // MFMA tile-rows per wave
    __shared__ bf16 As[128 * 32];
    __shared__ bf16 Bs[BN * 32];
    A += (size_t)blockIdx.z * ab;
    Bm += (size_t)blockIdx.z * bb;
    const int m0 = blockIdx.y * 128, n0 = blockIdx.x * BN;
    const int t = threadIdx.x, lane = t & 63, w = t >> 6;
    const int wm = (BN == 128) ? (w >> 1) * 64 : w * 32;
    const int wn = (BN == 128) ? (w & 1) * 64 : 0;
    const int q = lane >> 4, cl = lane & 15;
    // staging geometry: wave w covers rows [chunk*64 + w*16, +16), 32 cols
    const int srow = lane >> 2;        // 0..15
    const int scol = (lane & 3) * 8;   // 0,8,16,24
    const bf16* pa0 = A + (size_t)(m0 + w * 16 + srow) * lda + scol;
    const bf16* pa1 = pa0 + (size_t)64 * lda;
    const bf16* pb0 = Bm + (size_t)(n0 + w * 16 + srow) * ldb + scol;
    const bf16* pb1 = pb0 + (size_t)64 * ldb;
    bf16* lA0 = As + (w * 16) * 32;
    bf16* lA1 = As + (64 + w * 16) * 32;
    bf16* lB0 = Bs + (w * 16) * 32;
    bf16* lB1 = Bs + (64 + w * 16) * 32;

    f32x4 acc[TM][4] = {};
    for (int k0 = 0; k0 < K; k0 += 32) {
        gl_lds16(pa0 + k0, lA0);
        gl_lds16(pa1 + k0, lA1);
        gl_lds16(pb0 + k0, lB0);
        if constexpr (BN == 128) gl_lds16(pb1 + k0, lB1);
        __syncthreads();
        bf16x8 af[TM], bfr[4];
#pragma unroll
        for (int i = 0; i < TM; i++)
            af[i] = *(const bf16x8*)&As[(wm + i * 16 + cl) * 32 + q * 8];
#pragma unroll
        for (int j = 0; j < 4; j++)
            bfr[j] = *(const bf16x8*)&Bs[(wn + j * 16 + cl) * 32 + q * 8];
#pragma unroll
        for (int i = 0; i < TM; i++)
#pragma unroll
            for (int j = 0; j < 4; j++)
                acc[i][j] = __builtin_amdgcn_mfma_f32_16x16x32_bf16(af[i], bfr[j], acc[i][j], 0, 0, 0);
        __syncthreads();
    }

    if constexpr (EPI == 4 || EPI == 5) {
        // transposed pack-store epilogue: lane's 4 r-values are consecutive
        // rows -> contiguous along the target's minor dim.
        float inv[4], cs[4] = {0.f, 0.f, 0.f, 0.f};
        if constexpr (EPI == 5) {
#pragma unroll
            for (int j = 0; j < 4; j++)
                inv[j] = 1.0f / rowsum[(size_t)blockIdx.z * SS + n0 + wn + j * 16 + cl];
        }
#pragma unroll
        for (int i = 0; i < TM; i++)
#pragma unroll
            for (int j = 0; j < 4; j++) {
                int col = n0 + wn + j * 16 + cl;
                int row = m0 + wm + i * 16 + q * 4;
                bf16x4 o;
                if constexpr (EPI == 4) {
#pragma unroll
                    for (int r = 0; r < 4; r++) {
                        float e = __expf(acc[i][j][r] * scale);
                        cs[j] += e;
                        o[r] = (bf16)e;
                    }
                } else {
#pragma unroll
                    for (int r = 0; r < 4; r++) o[r] = (bf16)(acc[i][j][r] * inv[j]);
                }
                *(bf16x4*)&((bf16*)Cv)[(size_t)blockIdx.z * cb + (size_t)col * ldc + row] = o;
            }
        if constexpr (EPI == 4) {
            // reduce column sums across the 4 q-groups, then one atomic/col
#pragma unroll
            for (int j = 0; j < 4; j++) {
                cs[j] += __shfl_xor(cs[j], 16, 64);
                cs[j] += __shfl_xor(cs[j], 32, 64);
            }
            if (q == 0) {
#pragma unroll
                for (int j = 0; j < 4; j++)
                    atomicAdd(&rowsum[(size_t)blockIdx.z * SS + n0 + wn + j * 16 + cl], cs[j]);
            }
        }
        return;
    }

    const bool v_block = (EPI == 3) && (n0 >= 1024);
#pragma unroll
    for (int i = 0; i < TM; i++) {
#pragma unroll
        for (int j = 0; j < 4; j++) {
            int col = n0 + wn + j * 16 + cl;
            float bvv = bias ? bias[col] : 0.0f;
            if (v_block) {
                // rows are consecutive s -> pack b64 into vT
                int row = m0 + wm + i * 16 + q * 4;
                int b = row >> 11, s = row & 2047;
                bf16x4 o;
#pragma unroll
                for (int r = 0; r < 4; r++) o[r] = (bf16)(acc[i][j][r] * scale + bvv);
                *(bf16x4*)&vTp[((size_t)b * DD + (col - 1024)) * SS + s] = o;
            } else {
#pragma unroll
                for (int r = 0; r < 4; r++) {
                    int row = m0 + wm + i * 16 + q * 4 + r;
                    float val = acc[i][j][r] * scale + bvv;
                    if (OUT_BF16)
                        ((bf16*)Cv)[(size_t)blockIdx.z * cb + (size_t)row * ldc + col] = (bf16)val;
                    else
                        ((float*)Cv)[(size_t)blockIdx.z * cb + (size_t)row * ldc + col] = val;
                }
            }
        }
    }
}

// ---------------------------------------------------------------------------
extern "C" void kernel_launch(void* const* d_in, const int* in_sizes, int n_in,
                              void* d_out, int out_size, void* d_ws, size_t ws_size,
                              hipStream_t stream) {
    const float* x    = (const float*)d_in[0];  // (4,2048,2048)
    const float* Wqkv = (const float*)d_in[1];  // (1536,2048)
    const float* bqkv = (const float*)d_in[2];  // (1536,)
    const float* Wo   = (const float*)d_in[3];  // (2048,512)
    const float* bo   = (const float*)d_in[4];  // (2048,)
    float* out = (float*)d_out;                 // (4,2048,2048) fp32

    char* ws = (char*)d_ws;
    size_t off = 0;
    bf16* xb    = (bf16*)(ws + off); off += (size_t)MM * CC * 2;       // 32 MB
    bf16* wqkvb = (bf16*)(ws + off); off += (size_t)ND3 * CC * 2;      // 6 MB
    bf16* wob   = (bf16*)(ws + off); off += (size_t)CC * DD * 2;       // 2 MB
    bf16* qkvb  = (bf16*)(ws + off); off += (size_t)MM * ND3 * 2;      // 24 MB (v-third unused)
    bf16* vT    = (bf16*)(ws + off); off += (size_t)BB * DD * SS * 2;  // 8 MB
    bf16* expS  = (bf16*)(ws + off); off += (size_t)BB * SS * SS * 2;  // 32 MB
    bf16* ctxb  = (bf16*)(ws + off); off += (size_t)MM * DD * 2;       // 8 MB
    float* rsum = (float*)(ws + off); off += (size_t)MM * 4;           // 32 KB

    // 1. convert inputs to bf16 + zero rsum (one kernel)
    prep<<<2048, 256, 0, stream>>>(x, Wqkv, Wo, xb, wqkvb, wob, rsum);

    // 2. qkv = x Wqkv^T + bqkv; q,k -> qkvb rows, v -> vT transposed
    gemm_bt<true, 128, 3><<<dim3(ND3 / 128, MM / 128, 1), 256, 0, stream>>>(
        xb, wqkvb, bqkv, nullptr, vT, qkvb, CC, CC, CC, ND3, 0, 0, 0, 1.0f);

    // 3. expS[q][k] = exp(q k^T / sqrt(d)) via S^T = k q^T (A=k, B=q);
    //    packed b64 stores, rowsum accumulated per q-column
    gemm_bt<true, 128, 4><<<dim3(SS / 128, SS / 128, BB), 256, 0, stream>>>(
        qkvb + 512 /*k*/, qkvb /*q*/, nullptr, rsum, nullptr, expS,
        DD, ND3, ND3, SS,
        (long)SS * ND3, (long)SS * ND3, (long)SS * SS,
        0.044194173824159216f /* 1/sqrt(512) */);

    // 4. ctx[q][d] via ctx^T[d][q] = vT expS^T (A=vT M=512, B=expS N=2048,
    //    K=2048); divide by rowsum[col]; packed b64 stores into ctx[q][d]
    gemm_bt<true, 64, 5><<<dim3(SS / 64, DD / 128, BB), 256, 0, stream>>>(
        vT, expS, nullptr, rsum, nullptr, ctxb,
        SS, SS, SS, DD,
        (long)DD * SS, (long)SS * SS, (long)SS * DD, 1.0f);

    // 5. out = ctx Wo^T + bo  (M=8192, N=2048, K=512) -> fp32
    gemm_bt<false, 128, 0><<<dim3(CC / 128, MM / 128, 1), 256, 0, stream>>>(
        ctxb, wob, bo, nullptr, nullptr, out, DD, DD, DD, CC, 0, 0, 0, 1.0f);

    (void)in_sizes; (void)n_in; (void)out_size; (void)ws_size;
}

// Round 6
// 302.719 us; speedup vs baseline: 1.3958x; 1.0967x over previous
//
#include <hip/hip_runtime.h>
#include <math.h>

// ---------------------------------------------------------------------------
// SingleHeadSelfAttention: B=4, S=2048, C=2048, d=512
// R6: BK=64 K-loop (half the barrier drains), XOR-swizzled LDS layout
//     (required: [row][64] naive would 4-way bank-conflict; padding illegal
//     with global_load_lds). Distinct kernel names per GEMM role for rocprof.
// ---------------------------------------------------------------------------

typedef __bf16 bf16;
typedef bf16 bf16x8 __attribute__((ext_vector_type(8)));
typedef bf16 bf16x4 __attribute__((ext_vector_type(4)));
typedef float f32x4 __attribute__((ext_vector_type(4)));

#define BB 4
#define SS 2048
#define CC 2048
#define DD 512
#define ND3 1536          // 3*DD
#define MM 8192           // BB*SS

typedef const __attribute__((address_space(1))) unsigned int g_u32;
typedef __attribute__((address_space(3))) unsigned int l_u32;

__device__ __forceinline__ void gl_lds16(const bf16* g, bf16* l) {
    __builtin_amdgcn_global_load_lds((g_u32*)g, (l_u32*)l, 16, 0, 0);
}

// ---------------- prep: fp32->bf16 for x/Wqkv/Wo + zero rsum ---------------
#define N4_X   (MM * CC / 4)          // 4194304
#define N4_WQ  (ND3 * CC / 4)         //  786432
#define N4_WO  (CC * DD / 4)          //  262144
#define N4_RS  (MM / 4)               //    2048
#define N4_TOT (N4_X + N4_WQ + N4_WO + N4_RS)

__global__ __launch_bounds__(256) void prep(const float* __restrict__ x,
                                            const float* __restrict__ Wqkv,
                                            const float* __restrict__ Wo,
                                            bf16* __restrict__ xb,
                                            bf16* __restrict__ wqkvb,
                                            bf16* __restrict__ wob,
                                            float* __restrict__ rsum) {
    int i = blockIdx.x * 256 + threadIdx.x;
    const int stride = gridDim.x * 256;
    for (; i < N4_TOT; i += stride) {
        if (i < N4_X + N4_WQ + N4_WO) {
            const float* src; bf16* dst; int j = i;
            if (j < N4_X)                { src = x;    dst = xb; }
            else if (j < N4_X + N4_WQ)   { src = Wqkv; dst = wqkvb; j -= N4_X; }
            else                         { src = Wo;   dst = wob;   j -= N4_X + N4_WQ; }
            float4 v = ((const float4*)src)[j];
            bf16x4 o;
            o[0] = (bf16)v.x; o[1] = (bf16)v.y; o[2] = (bf16)v.z; o[3] = (bf16)v.w;
            ((bf16x4*)dst)[j] = o;
        } else {
            int j = i - (N4_X + N4_WQ + N4_WO);
            ((float4*)rsum)[j] = float4{0.f, 0.f, 0.f, 0.f};
        }
    }
}

// ---------------- C[m][n] = f( scale * sum_k A[m][k]B[n][k] ) --------------
// BM=128, BK=64. BN=128: 4 waves 2x2 (each 64x64, TM=4). BN=64: 4 waves 4x1
// (each 32x64, TM=2). Staging: global_load_lds width=16, 8 rows x 64 cols per
// instr; GLOBAL column-block XOR-swizzled by row (blk_g = blk_l ^ (row&7)) so
// the [row][64] unpadded LDS reads stay bank-uniform.
// EPI: 0 = scale*acc + bias[col], row-major stores
//      3 = QKV split: col<1024 row-major; col>=1024 transposed into vT
//      4 = scoresT: exp(scale*acc), packed b64 C^T store, col-sum atomics
//      5 = pvT: acc/rowsum[col], packed b64 C^T store
template <bool OUT_BF16, int BN, int EPI>
__device__ __forceinline__ void gemm_body(const bf16* __restrict__ A,
                                          const bf16* __restrict__ Bm,
                                          const float* __restrict__ bias,
                                          float* __restrict__ rowsum,
                                          bf16* __restrict__ vTp,
                                          void* __restrict__ Cv,
                                          int K, int lda, int ldb, int ldc,
                                          long ab, long bb, long cb,
                                          float scale) {
    constexpr int TM = (BN == 128) ? 4 : 2;     // MFMA tile-rows per wave
    constexpr int NB = (BN == 128) ? 4 : 2;     // B staging instrs per wave
    __shared__ bf16 As[128 * 64];
    __shared__ bf16 Bs[BN * 64];
    A += (size_t)blockIdx.z * ab;
    Bm += (size_t)blockIdx.z * bb;
    const int m0 = blockIdx.y * 128, n0 = blockIdx.x * BN;
    const int t = threadIdx.x, lane = t & 63, w = t >> 6;
    const int wm = (BN == 128) ? (w >> 1) * 64 : w * 32;
    const int wn = (BN == 128) ? (w & 1) * 64 : 0;
    const int q = lane >> 4, cl = lane & 15;
    // staging: instr covers 8 rows x 64 cols; lane -> row lane>>3, col-block
    // swizzled: gblk = (lane&7) ^ (lane>>3)
    const int srow = lane >> 3;                    // 0..7
    const int sblk = (lane & 7) ^ srow;            // global col block 0..7
    const int scol = sblk * 8;
    const bf16* pa = A + (size_t)(m0 + w * 32 + srow) * lda + scol;
    const int brow0 = (BN == 128) ? w * 32 : w * 16;
    const bf16* pb = Bm + (size_t)(n0 + brow0 + srow) * ldb + scol;
    bf16* lA = As + (w * 32) * 64;
    bf16* lB = Bs + brow0 * 64;
    // read-side swizzle: element offset within row for k-half h, quad q:
    // blk = (h*4+q) ^ (row&7); row&7 == cl&7 (wm, i*16 are 8-aligned)
    const int rblk0 = (q ^ (cl & 7)) * 8;          // h=0
    const int rblk1 = ((4 + q) ^ (cl & 7)) * 8;    // h=1

    f32x4 acc[TM][4] = {};
    for (int k0 = 0; k0 < K; k0 += 64) {
#pragma unroll
        for (int n = 0; n < 4; n++)
            gl_lds16(pa + k0 + (size_t)(n * 8) * lda, lA + n * 8 * 64);
#pragma unroll
        for (int n = 0; n < NB; n++)
            gl_lds16(pb + k0 + (size_t)(n * 8) * ldb, lB + n * 8 * 64);
        __syncthreads();
#pragma unroll
        for (int h = 0; h < 2; h++) {
            const int rb = h ? rblk1 : rblk0;
            bf16x8 af[TM], bfr[4];
#pragma unroll
            for (int i = 0; i < TM; i++)
                af[i] = *(const bf16x8*)&As[(wm + i * 16 + cl) * 64 + rb];
#pragma unroll
            for (int j = 0; j < 4; j++)
                bfr[j] = *(const bf16x8*)&Bs[(wn + j * 16 + cl) * 64 + rb];
#pragma unroll
            for (int i = 0; i < TM; i++)
#pragma unroll
                for (int j = 0; j < 4; j++)
                    acc[i][j] = __builtin_amdgcn_mfma_f32_16x16x32_bf16(af[i], bfr[j], acc[i][j], 0, 0, 0);
        }
        __syncthreads();
    }

    if constexpr (EPI == 4 || EPI == 5) {
        float inv[4], cs[4] = {0.f, 0.f, 0.f, 0.f};
        if constexpr (EPI == 5) {
#pragma unroll
            for (int j = 0; j < 4; j++)
                inv[j] = 1.0f / rowsum[(size_t)blockIdx.z * SS + n0 + wn + j * 16 + cl];
        }
#pragma unroll
        for (int i = 0; i < TM; i++)
#pragma unroll
            for (int j = 0; j < 4; j++) {
                int col = n0 + wn + j * 16 + cl;
                int row = m0 + wm + i * 16 + q * 4;
                bf16x4 o;
                if constexpr (EPI == 4) {
#pragma unroll
                    for (int r = 0; r < 4; r++) {
                        float e = __expf(acc[i][j][r] * scale);
                        cs[j] += e;
                        o[r] = (bf16)e;
                    }
                } else {
#pragma unroll
                    for (int r = 0; r < 4; r++) o[r] = (bf16)(acc[i][j][r] * inv[j]);
                }
                *(bf16x4*)&((bf16*)Cv)[(size_t)blockIdx.z * cb + (size_t)col * ldc + row] = o;
            }
        if constexpr (EPI == 4) {
#pragma unroll
            for (int j = 0; j < 4; j++) {
                cs[j] += __shfl_xor(cs[j], 16, 64);
                cs[j] += __shfl_xor(cs[j], 32, 64);
            }
            if (q == 0) {
#pragma unroll
                for (int j = 0; j < 4; j++)
                    atomicAdd(&rowsum[(size_t)blockIdx.z * SS + n0 + wn + j * 16 + cl], cs[j]);
            }
        }
        return;
    }

    const bool v_block = (EPI == 3) && (n0 >= 1024);
#pragma unroll
    for (int i = 0; i < TM; i++) {
#pragma unroll
        for (int j = 0; j < 4; j++) {
            int col = n0 + wn + j * 16 + cl;
            float bvv = bias ? bias[col] : 0.0f;
            if (v_block) {
                int row = m0 + wm + i * 16 + q * 4;
                int b = row >> 11, s = row & 2047;
                bf16x4 o;
#pragma unroll
                for (int r = 0; r < 4; r++) o[r] = (bf16)(acc[i][j][r] * scale + bvv);
                *(bf16x4*)&vTp[((size_t)b * DD + (col - 1024)) * SS + s] = o;
            } else {
#pragma unroll
                for (int r = 0; r < 4; r++) {
                    int row = m0 + wm + i * 16 + q * 4 + r;
                    float val = acc[i][j][r] * scale + bvv;
                    if (OUT_BF16)
                        ((bf16*)Cv)[(size_t)blockIdx.z * cb + (size_t)row * ldc + col] = (bf16)val;
                    else
                        ((float*)Cv)[(size_t)blockIdx.z * cb + (size_t)row * ldc + col] = val;
                }
            }
        }
    }
}

// distinct names so rocprof reports per-role counters
__global__ __launch_bounds__(256) void k_qkv(const bf16* A, const bf16* Bm,
        const float* bias, bf16* vTp, void* Cv, int K, int lda, int ldb, int ldc,
        float scale) {
    gemm_body<true, 128, 3>(A, Bm, bias, nullptr, vTp, Cv, K, lda, ldb, ldc, 0, 0, 0, scale);
}
__global__ __launch_bounds__(256) void k_score(const bf16* A, const bf16* Bm,
        float* rowsum, void* Cv, int K, int lda, int ldb, int ldc,
        long ab, long bb, long cb, float scale) {
    gemm_body<true, 128, 4>(A, Bm, nullptr, rowsum, nullptr, Cv, K, lda, ldb, ldc, ab, bb, cb, scale);
}
__global__ __launch_bounds__(256) void k_pv(const bf16* A, const bf16* Bm,
        float* rowsum, void* Cv, int K, int lda, int ldb, int ldc,
        long ab, long bb, long cb, float scale) {
    gemm_body<true, 64, 5>(A, Bm, nullptr, rowsum, nullptr, Cv, K, lda, ldb, ldc, ab, bb, cb, scale);
}
__global__ __launch_bounds__(256) void k_out(const bf16* A, const bf16* Bm,
        const float* bias, void* Cv, int K, int lda, int ldb, int ldc,
        float scale) {
    gemm_body<false, 128, 0>(A, Bm, bias, nullptr, nullptr, Cv, K, lda, ldb, ldc, 0, 0, 0, scale);
}

// ---------------------------------------------------------------------------
extern "C" void kernel_launch(void* const* d_in, const int* in_sizes, int n_in,
                              void* d_out, int out_size, void* d_ws, size_t ws_size,
                              hipStream_t stream) {
    const float* x    = (const float*)d_in[0];  // (4,2048,2048)
    const float* Wqkv = (const float*)d_in[1];  // (1536,2048)
    const float* bqkv = (const float*)d_in[2];  // (1536,)
    const float* Wo   = (const float*)d_in[3];  // (2048,512)
    const float* bo   = (const float*)d_in[4];  // (2048,)
    float* out = (float*)d_out;                 // (4,2048,2048) fp32

    char* ws = (char*)d_ws;
    size_t off = 0;
    bf16* xb    = (bf16*)(ws + off); off += (size_t)MM * CC * 2;       // 32 MB
    bf16* wqkvb = (bf16*)(ws + off); off += (size_t)ND3 * CC * 2;      // 6 MB
    bf16* wob   = (bf16*)(ws + off); off += (size_t)CC * DD * 2;       // 2 MB
    bf16* qkvb  = (bf16*)(ws + off); off += (size_t)MM * ND3 * 2;      // 24 MB
    bf16* vT    = (bf16*)(ws + off); off += (size_t)BB * DD * SS * 2;  // 8 MB
    bf16* expS  = (bf16*)(ws + off); off += (size_t)BB * SS * SS * 2;  // 32 MB
    bf16* ctxb  = (bf16*)(ws + off); off += (size_t)MM * DD * 2;       // 8 MB
    float* rsum = (float*)(ws + off); off += (size_t)MM * 4;           // 32 KB

    // 1. convert inputs to bf16 + zero rsum
    prep<<<2048, 256, 0, stream>>>(x, Wqkv, Wo, xb, wqkvb, wob, rsum);

    // 2. qkv = x Wqkv^T + bqkv; q,k -> qkvb rows, v -> vT transposed
    k_qkv<<<dim3(ND3 / 128, MM / 128, 1), 256, 0, stream>>>(
        xb, wqkvb, bqkv, vT, qkvb, CC, CC, CC, ND3, 1.0f);

    // 3. expS[q][k] = exp(q k^T / sqrt(d)) via S^T = k q^T; col-sum atomics
    k_score<<<dim3(SS / 128, SS / 128, BB), 256, 0, stream>>>(
        qkvb + 512 /*k*/, qkvb /*q*/, rsum, expS,
        DD, ND3, ND3, SS,
        (long)SS * ND3, (long)SS * ND3, (long)SS * SS,
        0.044194173824159216f /* 1/sqrt(512) */);

    // 4. ctx[q][d] via ctx^T = vT expS^T; /rowsum[col]; packed stores
    k_pv<<<dim3(SS / 64, DD / 128, BB), 256, 0, stream>>>(
        vT, expS, rsum, ctxb,
        SS, SS, SS, DD,
        (long)DD * SS, (long)SS * SS, (long)SS * DD, 1.0f);

    // 5. out = ctx Wo^T + bo  (M=8192, N=2048, K=512) -> fp32
    k_out<<<dim3(CC / 128, MM / 128, 1), 256, 0, stream>>>(
        ctxb, wob, bo, out, DD, DD, DD, CC, 1.0f);

    (void)in_sizes; (void)n_in; (void)out_size; (void)ws_size;
}